// Round 1
// baseline (256.052 us; speedup 1.0000x reference)
//
#include <hip/hip_runtime.h>
#include <stdint.h>

#define FD 2048

typedef short short8 __attribute__((ext_vector_type(8)));
typedef float f32x4 __attribute__((ext_vector_type(4)));
typedef unsigned short ushort_t;

__device__ __forceinline__ unsigned bf16_rne(float f) {
  unsigned u = __float_as_uint(f);
  return (u + 0x7FFFu + ((u >> 16) & 1u)) >> 16;
}

// ---- prep: build v_hi/v_lo bf16 fragments in MFMA B-layout + S2 table ----
// Fragment layout: for k-step s (0..63), col-tile c (0..3), lane l (0..63),
// elem j (0..7): element v[s*32 + (l>>4)*8 + j][c*16 + (l&15)] stored at
// flat index ((s*4 + c)*64 + l)*8 + j   (16B per lane -> one dwordx4 load).
__global__ __launch_bounds__(256) void fm_prep(
    const float* __restrict__ v, ushort_t* __restrict__ hi,
    ushort_t* __restrict__ lo, float* __restrict__ s2t)
{
  int bid = blockIdx.x;
  if (bid < 512) {
    int t = bid * 256 + threadIdx.x;       // bf16 element index 0..131071
    int j    = t & 7;
    int lane = (t >> 3) & 63;
    int c    = (t >> 9) & 3;
    int s    = t >> 11;
    int k    = s * 32 + ((lane >> 4) << 3) + j;
    int col  = (c << 4) + (lane & 15);
    float val = v[k * 64 + col];
    unsigned hb = bf16_rne(val);
    float hf = __uint_as_float(hb << 16);
    unsigned lb = bf16_rne(val - hf);
    hi[t] = (ushort_t)hb;
    lo[t] = (ushort_t)lb;
  } else {
    int k = (bid - 512) * 256 + threadIdx.x;   // 0..2047
    const float4* row = (const float4*)(v + k * 64);
    float s = 0.f;
    #pragma unroll
    for (int i = 0; i < 16; ++i) {
      float4 q = row[i];
      s += q.x * q.x + q.y * q.y + q.z * q.z + q.w * q.w;
    }
    s2t[k] = s;
  }
}

// ---- main: 512 WGs x 512 thr; WG = 32 rows; wave w owns k in [w*256,(w+1)*256) ----
__global__ __launch_bounds__(512) void fm_main(
    const float* __restrict__ x, const float* __restrict__ w,
    const float* __restrict__ bptr, const short8* __restrict__ vhi,
    const short8* __restrict__ vlo, const float* __restrict__ s2t,
    float* __restrict__ out)
{
  __shared__ float lds_xv[32][64];
  __shared__ float lds_lin[32];
  __shared__ float lds_q[32];

  const int tid = threadIdx.x;
  const int wv  = tid >> 6;        // wave 0..7 -> K chunk
  const int l   = tid & 63;
  const int l15 = l & 15;
  const int lk  = l >> 4;          // 0..3 k-group
  const int R   = blockIdx.x << 5; // 32 rows per WG
  const int kbase = wv << 8;       // wave's K origin

  {
    float* z = &lds_xv[0][0];
    #pragma unroll
    for (int i = tid; i < 32 * 64; i += 512) z[i] = 0.f;
    if (tid < 32) { lds_lin[tid] = 0.f; lds_q[tid] = 0.f; }
  }
  __syncthreads();

  const float* px0 = x + (size_t)(R + l15) * FD + kbase + (lk << 3);
  const float* px1 = px0 + (size_t)16 * FD;
  const float* pw  = w   + kbase + (lk << 3);
  const float* ps  = s2t + kbase + (lk << 3);

  f32x4 acc[2][4];
  #pragma unroll
  for (int t = 0; t < 2; ++t)
    #pragma unroll
    for (int c = 0; c < 4; ++c)
      acc[t][c] = (f32x4){0.f, 0.f, 0.f, 0.f};

  float lin0 = 0.f, lin1 = 0.f, q0 = 0.f, q1 = 0.f;

  #pragma unroll
  for (int st = 0; st < 8; ++st) {
    const int ko = st << 5;
    float4 a0 = *(const float4*)(px0 + ko);
    float4 a1 = *(const float4*)(px0 + ko + 4);
    float4 b0 = *(const float4*)(px1 + ko);
    float4 b1 = *(const float4*)(px1 + ko + 4);
    float4 w0 = *(const float4*)(pw + ko);
    float4 w1 = *(const float4*)(pw + ko + 4);
    float4 s0 = *(const float4*)(ps + ko);
    float4 s1 = *(const float4*)(ps + ko + 4);

    const int sg = (wv << 3) + st;   // global k-step 0..63
    short8 bh[4], bl[4];
    #pragma unroll
    for (int c = 0; c < 4; ++c) {
      bh[c] = vhi[(sg * 4 + c) * 64 + l];
      bl[c] = vlo[(sg * 4 + c) * 64 + l];
    }

    float fa[8] = {a0.x, a0.y, a0.z, a0.w, a1.x, a1.y, a1.z, a1.w};
    float fb[8] = {b0.x, b0.y, b0.z, b0.w, b1.x, b1.y, b1.z, b1.w};
    float fw[8] = {w0.x, w0.y, w0.z, w0.w, w1.x, w1.y, w1.z, w1.w};
    float fs[8] = {s0.x, s0.y, s0.z, s0.w, s1.x, s1.y, s1.z, s1.w};

    short8 ah0, al0, ah1, al1;
    #pragma unroll
    for (int j = 0; j < 8; ++j) {
      unsigned h0 = bf16_rne(fa[j]);
      ah0[j] = (short)h0;
      al0[j] = (short)bf16_rne(fa[j] - __uint_as_float(h0 << 16));
      lin0 = fmaf(fa[j], fw[j], lin0);
      q0   = fmaf(fa[j] * fa[j], fs[j], q0);
      unsigned h1 = bf16_rne(fb[j]);
      ah1[j] = (short)h1;
      al1[j] = (short)bf16_rne(fb[j] - __uint_as_float(h1 << 16));
      lin1 = fmaf(fb[j], fw[j], lin1);
      q1   = fmaf(fb[j] * fb[j], fs[j], q1);
    }

    #pragma unroll
    for (int c = 0; c < 4; ++c) {
      acc[0][c] = __builtin_amdgcn_mfma_f32_16x16x32_bf16(ah0, bh[c], acc[0][c], 0, 0, 0);
      acc[0][c] = __builtin_amdgcn_mfma_f32_16x16x32_bf16(al0, bh[c], acc[0][c], 0, 0, 0);
      acc[0][c] = __builtin_amdgcn_mfma_f32_16x16x32_bf16(ah0, bl[c], acc[0][c], 0, 0, 0);
      acc[1][c] = __builtin_amdgcn_mfma_f32_16x16x32_bf16(ah1, bh[c], acc[1][c], 0, 0, 0);
      acc[1][c] = __builtin_amdgcn_mfma_f32_16x16x32_bf16(al1, bh[c], acc[1][c], 0, 0, 0);
      acc[1][c] = __builtin_amdgcn_mfma_f32_16x16x32_bf16(ah1, bl[c], acc[1][c], 0, 0, 0);
    }
  }

  // reduce lin/q over the 4 k-groups sharing a row (lanes l ^ {16,32})
  lin0 += __shfl_xor(lin0, 16, 64); lin0 += __shfl_xor(lin0, 32, 64);
  lin1 += __shfl_xor(lin1, 16, 64); lin1 += __shfl_xor(lin1, 32, 64);
  q0   += __shfl_xor(q0,   16, 64); q0   += __shfl_xor(q0,   32, 64);
  q1   += __shfl_xor(q1,   16, 64); q1   += __shfl_xor(q1,   32, 64);
  if (lk == 0) {
    atomicAdd(&lds_lin[l15],      lin0);
    atomicAdd(&lds_lin[16 + l15], lin1);
    atomicAdd(&lds_q[l15],        q0);
    atomicAdd(&lds_q[16 + l15],   q1);
  }

  // accumulate partial xv into LDS (C/D layout: col=l&15, row=(l>>4)*4+j)
  #pragma unroll
  for (int t = 0; t < 2; ++t)
    #pragma unroll
    for (int c = 0; c < 4; ++c)
      #pragma unroll
      for (int j = 0; j < 4; ++j)
        atomicAdd(&lds_xv[t * 16 + lk * 4 + j][c * 16 + l15], acc[t][c][j]);

  __syncthreads();

  // final: thread -> (row = tid>>4, colgroup = tid&15); reduce cols, sigmoid
  {
    const int row = tid >> 4;
    const int cg  = tid & 15;
    float4 s = *(const float4*)&lds_xv[row][cg << 2];
    float ss = s.x * s.x + s.y * s.y + s.z * s.z + s.w * s.w;
    ss += __shfl_xor(ss, 1, 64);
    ss += __shfl_xor(ss, 2, 64);
    ss += __shfl_xor(ss, 4, 64);
    ss += __shfl_xor(ss, 8, 64);
    if (cg == 0) {
      float z = lds_lin[row] + bptr[0] + 0.5f * (ss - lds_q[row]);
      out[R + row] = 1.f / (1.f + expf(-z));
    }
  }
}

extern "C" void kernel_launch(void* const* d_in, const int* in_sizes, int n_in,
                              void* d_out, int out_size, void* d_ws, size_t ws_size,
                              hipStream_t stream) {
  const float* x = (const float*)d_in[0];
  const float* w = (const float*)d_in[1];
  const float* b = (const float*)d_in[2];
  const float* v = (const float*)d_in[3];
  float* out = (float*)d_out;

  // ws layout: [0,256K) v_hi bf16 frags | [256K,512K) v_lo | [512K,520K) S2 f32
  ushort_t* hi = (ushort_t*)d_ws;
  ushort_t* lo = hi + FD * 64;
  float*    s2 = (float*)((char*)d_ws + (size_t)FD * 64 * 2 * sizeof(ushort_t));

  fm_prep<<<520, 256, 0, stream>>>(v, hi, lo, s2);
  fm_main<<<512, 512, 0, stream>>>(x, w, b, (const short8*)hi, (const short8*)lo, s2, out);
}

// Round 3
// 246.016 us; speedup vs baseline: 1.0408x; 1.0408x over previous
//
#include <hip/hip_runtime.h>
#include <stdint.h>

#define FD 2048

typedef short short8 __attribute__((ext_vector_type(8)));
typedef float f32x4 __attribute__((ext_vector_type(4)));
typedef unsigned short ushort_t;

__device__ __forceinline__ unsigned bf16_rne(float f) {
  unsigned u = __float_as_uint(f);
  return (u + 0x7FFFu + ((u >> 16) & 1u)) >> 16;
}

// ---- prep: build v_hi/v_lo bf16 fragments in MFMA B-layout + S2 table ----
// Element v[s*32 + (l>>4)*8 + j][c*16 + (l&15)] stored at flat index
// ((s*4 + c)*64 + l)*8 + j  (16B per lane -> one dwordx4 load in fm_main).
__global__ __launch_bounds__(256) void fm_prep(
    const float* __restrict__ v, ushort_t* __restrict__ hi,
    ushort_t* __restrict__ lo, float* __restrict__ s2t)
{
  int bid = blockIdx.x;
  if (bid < 512) {
    int t = bid * 256 + threadIdx.x;       // bf16 element index 0..131071
    int j    = t & 7;
    int lane = (t >> 3) & 63;
    int c    = (t >> 9) & 3;
    int s    = t >> 11;
    int k    = s * 32 + ((lane >> 4) << 3) + j;
    int col  = (c << 4) + (lane & 15);
    float val = v[k * 64 + col];
    unsigned hb = bf16_rne(val);
    float hf = __uint_as_float(hb << 16);
    unsigned lb = bf16_rne(val - hf);
    hi[t] = (ushort_t)hb;
    lo[t] = (ushort_t)lb;
  } else {
    int k = (bid - 512) * 256 + threadIdx.x;   // 0..2047
    const float4* row = (const float4*)(v + k * 64);
    float s = 0.f;
    #pragma unroll
    for (int i = 0; i < 16; ++i) {
      float4 q = row[i];
      s += q.x * q.x + q.y * q.y + q.z * q.z + q.w * q.w;
    }
    s2t[k] = s;
  }
}

// convert 8 floats -> hi/lo bf16 fragments (scalar RNE), accumulate lin/q
__device__ __forceinline__ void cvt_row(
    const float4& A0, const float4& A1,
    const float4& W0, const float4& W1,
    const float4& S0, const float4& S1,
    short8& H, short8& L, float& lin, float& q)
{
  float f[8]  = {A0.x, A0.y, A0.z, A0.w, A1.x, A1.y, A1.z, A1.w};
  float fw[8] = {W0.x, W0.y, W0.z, W0.w, W1.x, W1.y, W1.z, W1.w};
  float fs[8] = {S0.x, S0.y, S0.z, S0.w, S1.x, S1.y, S1.z, S1.w};
  #pragma unroll
  for (int j = 0; j < 8; ++j) {
    unsigned h = bf16_rne(f[j]);
    H[j] = (short)h;
    L[j] = (short)bf16_rne(f[j] - __uint_as_float(h << 16));
    lin = fmaf(f[j], fw[j], lin);
    q   = fmaf(f[j] * f[j], fs[j], q);
  }
}

#define MF(accv, a, b) accv = __builtin_amdgcn_mfma_f32_16x16x32_bf16(a, b, accv, 0, 0, 0)

// ---- main: 512 WGs x 512 thr; WG = 32 rows; wave w owns k in [w*256,(w+1)*256) ----
__global__ __launch_bounds__(512, 4) void fm_main(
    const float* __restrict__ x, const float* __restrict__ w,
    const float* __restrict__ bptr, const short8* __restrict__ vhi,
    const short8* __restrict__ vlo, const float* __restrict__ s2t,
    float* __restrict__ out)
{
  __shared__ float lds_w[FD];
  __shared__ float lds_s[FD];
  __shared__ float lds_xv[32][64];
  __shared__ float lds_lin[32];
  __shared__ float lds_q[32];

  const int tid = threadIdx.x;
  const int wv  = tid >> 6;        // wave 0..7 -> K chunk
  const int l   = tid & 63;
  const int l15 = l & 15;
  const int lk  = l >> 4;          // 0..3 k-group
  const int R   = blockIdx.x << 5; // 32 rows per WG
  const int kbase = wv << 8;       // wave's K origin

  {
    float* z = &lds_xv[0][0];
    #pragma unroll
    for (int i = tid; i < 32 * 64; i += 512) z[i] = 0.f;
    if (tid < 32) { lds_lin[tid] = 0.f; lds_q[tid] = 0.f; }
    // stage w and s2 (2048 floats each; 512 thr x 1 float4)
    *(float4*)&lds_w[tid << 2] = *(const float4*)(w + (tid << 2));
    *(float4*)&lds_s[tid << 2] = *(const float4*)(s2t + (tid << 2));
  }
  __syncthreads();

  const float* px0 = x + (size_t)(R + l15) * FD + kbase + (lk << 3);
  const float* px1 = px0 + (size_t)16 * FD;
  const int wsoff = kbase + (lk << 3);          // offset into lds_w / lds_s
  const short8* pb = vhi + (size_t)wv * 2048 + l;  // [st*256 + c*64]
  const short8* pl = vlo + (size_t)wv * 2048 + l;

  f32x4 acc[2][4];
  #pragma unroll
  for (int t = 0; t < 2; ++t)
    #pragma unroll
    for (int c = 0; c < 4; ++c)
      acc[t][c] = (f32x4){0.f, 0.f, 0.f, 0.f};

  float lin0 = 0.f, lin1 = 0.f, q0 = 0.f, q1 = 0.f;

  // prologue: load + convert step 0
  short8 cah0, cal0, cah1, cal1;
  {
    float4 a0 = *(const float4*)(px0);
    float4 a1 = *(const float4*)(px0 + 4);
    float4 b0 = *(const float4*)(px1);
    float4 b1 = *(const float4*)(px1 + 4);
    float4 wa = *(const float4*)&lds_w[wsoff];
    float4 wb = *(const float4*)&lds_w[wsoff + 4];
    float4 sa = *(const float4*)&lds_s[wsoff];
    float4 sb = *(const float4*)&lds_s[wsoff + 4];
    cvt_row(a0, a1, wa, wb, sa, sb, cah0, cal0, lin0, q0);
    cvt_row(b0, b1, wa, wb, sa, sb, cah1, cal1, lin1, q1);
  }

  #pragma unroll
  for (int st = 0; st < 8; ++st) {
    // ---- prefetch next step's x (issue early; consumed at end of this step)
    float4 na0, na1, nb0, nb1;
    if (st < 7) {
      const int nko = (st + 1) << 5;
      na0 = *(const float4*)(px0 + nko);
      na1 = *(const float4*)(px0 + nko + 4);
      nb0 = *(const float4*)(px1 + nko);
      nb1 = *(const float4*)(px1 + nko + 4);
    }

    // ---- B hi fragments for this step (L2-hot)
    short8 bh0 = pb[st * 256 + 0];
    short8 bh1 = pb[st * 256 + 64];
    short8 bh2 = pb[st * 256 + 128];
    short8 bh3 = pb[st * 256 + 192];

    // pass 1+2: hi*hi and lo*hi
    MF(acc[0][0], cah0, bh0); MF(acc[0][1], cah0, bh1);
    MF(acc[0][2], cah0, bh2); MF(acc[0][3], cah0, bh3);
    MF(acc[1][0], cah1, bh0); MF(acc[1][1], cah1, bh1);
    MF(acc[1][2], cah1, bh2); MF(acc[1][3], cah1, bh3);
    MF(acc[0][0], cal0, bh0); MF(acc[0][1], cal0, bh1);
    MF(acc[0][2], cal0, bh2); MF(acc[0][3], cal0, bh3);
    MF(acc[1][0], cal1, bh0); MF(acc[1][1], cal1, bh1);
    MF(acc[1][2], cal1, bh2); MF(acc[1][3], cal1, bh3);

    // ---- B lo fragments (loaded late to cap register liveness)
    short8 bl0 = pl[st * 256 + 0];
    short8 bl1 = pl[st * 256 + 64];
    short8 bl2 = pl[st * 256 + 128];
    short8 bl3 = pl[st * 256 + 192];

    // pass 3: hi*lo
    MF(acc[0][0], cah0, bl0); MF(acc[0][1], cah0, bl1);
    MF(acc[0][2], cah0, bl2); MF(acc[0][3], cah0, bl3);
    MF(acc[1][0], cah1, bl0); MF(acc[1][1], cah1, bl1);
    MF(acc[1][2], cah1, bl2); MF(acc[1][3], cah1, bl3);

    // ---- convert next step's x into carried fragments (+ lin/q)
    if (st < 7) {
      const int nws = wsoff + ((st + 1) << 5);
      float4 wa = *(const float4*)&lds_w[nws];
      float4 wb = *(const float4*)&lds_w[nws + 4];
      float4 sa = *(const float4*)&lds_s[nws];
      float4 sb = *(const float4*)&lds_s[nws + 4];
      cvt_row(na0, na1, wa, wb, sa, sb, cah0, cal0, lin0, q0);
      cvt_row(nb0, nb1, wa, wb, sa, sb, cah1, cal1, lin1, q1);
    }
  }

  // reduce lin/q over the 4 k-groups sharing a row (lanes l ^ {16,32})
  lin0 += __shfl_xor(lin0, 16, 64); lin0 += __shfl_xor(lin0, 32, 64);
  lin1 += __shfl_xor(lin1, 16, 64); lin1 += __shfl_xor(lin1, 32, 64);
  q0   += __shfl_xor(q0,   16, 64); q0   += __shfl_xor(q0,   32, 64);
  q1   += __shfl_xor(q1,   16, 64); q1   += __shfl_xor(q1,   32, 64);
  if (lk == 0) {
    atomicAdd(&lds_lin[l15],      lin0);
    atomicAdd(&lds_lin[16 + l15], lin1);
    atomicAdd(&lds_q[l15],        q0);
    atomicAdd(&lds_q[16 + l15],   q1);
  }

  // accumulate partial xv into LDS (C/D layout: col=l&15, row=(l>>4)*4+j)
  #pragma unroll
  for (int t = 0; t < 2; ++t)
    #pragma unroll
    for (int c = 0; c < 4; ++c)
      #pragma unroll
      for (int j = 0; j < 4; ++j)
        atomicAdd(&lds_xv[t * 16 + lk * 4 + j][c * 16 + l15], acc[t][c][j]);

  __syncthreads();

  // final: thread -> (row = tid>>4, colgroup = tid&15); reduce cols, sigmoid
  {
    const int row = tid >> 4;
    const int cg  = tid & 15;
    float4 s = *(const float4*)&lds_xv[row][cg << 2];
    float ss = s.x * s.x + s.y * s.y + s.z * s.z + s.w * s.w;
    ss += __shfl_xor(ss, 1, 64);
    ss += __shfl_xor(ss, 2, 64);
    ss += __shfl_xor(ss, 4, 64);
    ss += __shfl_xor(ss, 8, 64);
    if (cg == 0) {
      float z = lds_lin[row] + bptr[0] + 0.5f * (ss - lds_q[row]);
      out[R + row] = 1.f / (1.f + expf(-z));
    }
  }
}

extern "C" void kernel_launch(void* const* d_in, const int* in_sizes, int n_in,
                              void* d_out, int out_size, void* d_ws, size_t ws_size,
                              hipStream_t stream) {
  const float* x = (const float*)d_in[0];
  const float* w = (const float*)d_in[1];
  const float* b = (const float*)d_in[2];
  const float* v = (const float*)d_in[3];
  float* out = (float*)d_out;

  // ws layout: [0,256K) v_hi bf16 frags | [256K,512K) v_lo | [512K,520K) S2 f32
  ushort_t* hi = (ushort_t*)d_ws;
  ushort_t* lo = hi + FD * 64;
  float*    s2 = (float*)((char*)d_ws + (size_t)FD * 64 * 2 * sizeof(ushort_t));

  fm_prep<<<520, 256, 0, stream>>>(v, hi, lo, s2);
  fm_main<<<512, 512, 0, stream>>>(x, w, b, (const short8*)hi, (const short8*)lo, s2, out);
}

// Round 4
// 244.811 us; speedup vs baseline: 1.0459x; 1.0049x over previous
//
#include <hip/hip_runtime.h>
#include <stdint.h>

#define FD 2048

typedef short short8 __attribute__((ext_vector_type(8)));
typedef float f32x4 __attribute__((ext_vector_type(4)));
typedef unsigned short ushort_t;

__device__ __forceinline__ unsigned bf16_rne(float f) {
  unsigned u = __float_as_uint(f);
  return (u + 0x7FFFu + ((u >> 16) & 1u)) >> 16;
}

// ---- prep: build v_hi/v_lo bf16 fragments in MFMA B-layout + S2 table ----
// Element v[s*32 + (l>>4)*8 + j][c*16 + (l&15)] stored at flat index
// ((s*4 + c)*64 + l)*8 + j  (16B per lane -> one dwordx4 load in fm_main).
__global__ __launch_bounds__(256) void fm_prep(
    const float* __restrict__ v, ushort_t* __restrict__ hi,
    ushort_t* __restrict__ lo, float* __restrict__ s2t)
{
  int bid = blockIdx.x;
  if (bid < 512) {
    int t = bid * 256 + threadIdx.x;       // bf16 element index 0..131071
    int j    = t & 7;
    int lane = (t >> 3) & 63;
    int c    = (t >> 9) & 3;
    int s    = t >> 11;
    int k    = s * 32 + ((lane >> 4) << 3) + j;
    int col  = (c << 4) + (lane & 15);
    float val = v[k * 64 + col];
    unsigned hb = bf16_rne(val);
    float hf = __uint_as_float(hb << 16);
    unsigned lb = bf16_rne(val - hf);
    hi[t] = (ushort_t)hb;
    lo[t] = (ushort_t)lb;
  } else {
    int k = (bid - 512) * 256 + threadIdx.x;   // 0..2047
    const float4* row = (const float4*)(v + k * 64);
    float s = 0.f;
    #pragma unroll
    for (int i = 0; i < 16; ++i) {
      float4 q = row[i];
      s += q.x * q.x + q.y * q.y + q.z * q.z + q.w * q.w;
    }
    s2t[k] = s;
  }
}

// convert 8 floats -> hi/lo bf16 fragments (scalar RNE), accumulate lin/q
__device__ __forceinline__ void cvt_row(
    const float4& A0, const float4& A1,
    const float4& W0, const float4& W1,
    const float4& S0, const float4& S1,
    short8& H, short8& L, float& lin, float& q)
{
  float f[8]  = {A0.x, A0.y, A0.z, A0.w, A1.x, A1.y, A1.z, A1.w};
  float fw[8] = {W0.x, W0.y, W0.z, W0.w, W1.x, W1.y, W1.z, W1.w};
  float fs[8] = {S0.x, S0.y, S0.z, S0.w, S1.x, S1.y, S1.z, S1.w};
  #pragma unroll
  for (int j = 0; j < 8; ++j) {
    unsigned h = bf16_rne(f[j]);
    H[j] = (short)h;
    L[j] = (short)bf16_rne(f[j] - __uint_as_float(h << 16));
    lin = fmaf(f[j], fw[j], lin);
    q   = fmaf(f[j] * f[j], fs[j], q);
  }
}

#define MF(accv, a, b) accv = __builtin_amdgcn_mfma_f32_16x16x32_bf16(a, b, accv, 0, 0, 0)

// ---- main: 512 WGs x 512 thr; WG = 32 rows; wave w owns k in [w*256,(w+1)*256)
// Load-queue discipline (vmcnt is ORDERED): per iter, consume order is
//   x(st) [cvt, top] -> bh(st) [p1/p2] -> bl(st) [p3]
// and issue order at iter bottom is bh(st+1), bl(st+1), x(st+2), so each
// consumer's counted wait never drains the deep x prefetch.
__global__ __launch_bounds__(512, 3) void fm_main(
    const float* __restrict__ x, const float* __restrict__ w,
    const float* __restrict__ bptr, const short8* __restrict__ vhi,
    const short8* __restrict__ vlo, const float* __restrict__ s2t,
    float* __restrict__ out)
{
  __shared__ float lds_w[FD];
  __shared__ float lds_s[FD];
  __shared__ float lds_xv[32][64];
  __shared__ float lds_lin[32];
  __shared__ float lds_q[32];

  const int tid = threadIdx.x;
  const int wv  = tid >> 6;        // wave 0..7 -> K chunk
  const int l   = tid & 63;
  const int l15 = l & 15;
  const int lk  = l >> 4;          // 0..3 k-group
  const int R   = blockIdx.x << 5; // 32 rows per WG
  const int kbase = wv << 8;       // wave's K origin

  {
    float* z = &lds_xv[0][0];
    #pragma unroll
    for (int i = tid; i < 32 * 64; i += 512) z[i] = 0.f;
    if (tid < 32) { lds_lin[tid] = 0.f; lds_q[tid] = 0.f; }
    *(float4*)&lds_w[tid << 2] = *(const float4*)(w + (tid << 2));
    *(float4*)&lds_s[tid << 2] = *(const float4*)(s2t + (tid << 2));
  }
  __syncthreads();

  const float* px0 = x + (size_t)(R + l15) * FD + kbase + (lk << 3);
  const float* px1 = px0 + (size_t)16 * FD;
  const int wsoff = kbase + (lk << 3);             // offset into lds_w / lds_s
  const short8* pb = vhi + (size_t)wv * 2048 + l;  // frag (st,c) at st*256 + c*64
  const short8* pl = vlo + (size_t)wv * 2048 + l;

  f32x4 acc[2][4];
  #pragma unroll
  for (int t = 0; t < 2; ++t)
    #pragma unroll
    for (int c = 0; c < 4; ++c)
      acc[t][c] = (f32x4){0.f, 0.f, 0.f, 0.f};

  float lin0 = 0.f, lin1 = 0.f, q0 = 0.f, q1 = 0.f;

  // x double buffer [parity][half]; bh/bl single-buffered
  float4 xa[2][2], xb[2][2];
  short8 bh0, bh1, bh2, bh3, bl0, bl1, bl2, bl3;

  // ---- prologue (issue order = consume order): x(0), bh(0), bl(0), x(1)
  xa[0][0] = *(const float4*)(px0);
  xa[0][1] = *(const float4*)(px0 + 4);
  xb[0][0] = *(const float4*)(px1);
  xb[0][1] = *(const float4*)(px1 + 4);
  bh0 = pb[0];  bh1 = pb[64];  bh2 = pb[128];  bh3 = pb[192];
  bl0 = pl[0];  bl1 = pl[64];  bl2 = pl[128];  bl3 = pl[192];
  xa[1][0] = *(const float4*)(px0 + 32);
  xa[1][1] = *(const float4*)(px0 + 36);
  xb[1][0] = *(const float4*)(px1 + 32);
  xb[1][1] = *(const float4*)(px1 + 36);

  #pragma unroll
  for (int st = 0; st < 8; ++st) {
    const int cur = st & 1;

    // ---- top: convert x(st) (issued 2 iters ago) -> A frags, + lin/q
    short8 cah0, cal0, cah1, cal1;
    {
      const int ws = wsoff + (st << 5);
      float4 wa = *(const float4*)&lds_w[ws];
      float4 wb = *(const float4*)&lds_w[ws + 4];
      float4 sa = *(const float4*)&lds_s[ws];
      float4 sb = *(const float4*)&lds_s[ws + 4];
      cvt_row(xa[cur][0], xa[cur][1], wa, wb, sa, sb, cah0, cal0, lin0, q0);
      cvt_row(xb[cur][0], xb[cur][1], wa, wb, sa, sb, cah1, cal1, lin1, q1);
    }

    // ---- p1+p2: hi*hi, lo*hi (consumes bh(st), issued 1 iter ago)
    MF(acc[0][0], cah0, bh0); MF(acc[0][1], cah0, bh1);
    MF(acc[0][2], cah0, bh2); MF(acc[0][3], cah0, bh3);
    MF(acc[1][0], cah1, bh0); MF(acc[1][1], cah1, bh1);
    MF(acc[1][2], cah1, bh2); MF(acc[1][3], cah1, bh3);
    MF(acc[0][0], cal0, bh0); MF(acc[0][1], cal0, bh1);
    MF(acc[0][2], cal0, bh2); MF(acc[0][3], cal0, bh3);
    MF(acc[1][0], cal1, bh0); MF(acc[1][1], cal1, bh1);
    MF(acc[1][2], cal1, bh2); MF(acc[1][3], cal1, bh3);

    // ---- p3: hi*lo (consumes bl(st))
    MF(acc[0][0], cah0, bl0); MF(acc[0][1], cah0, bl1);
    MF(acc[0][2], cah0, bl2); MF(acc[0][3], cah0, bl3);
    MF(acc[1][0], cah1, bl0); MF(acc[1][1], cah1, bl1);
    MF(acc[1][2], cah1, bl2); MF(acc[1][3], cah1, bl3);

    // ---- bottom: issue bh(st+1), bl(st+1), then x(st+2)
    if (st < 7) {
      bh0 = pb[(st + 1) * 256 + 0];
      bh1 = pb[(st + 1) * 256 + 64];
      bh2 = pb[(st + 1) * 256 + 128];
      bh3 = pb[(st + 1) * 256 + 192];
      bl0 = pl[(st + 1) * 256 + 0];
      bl1 = pl[(st + 1) * 256 + 64];
      bl2 = pl[(st + 1) * 256 + 128];
      bl3 = pl[(st + 1) * 256 + 192];
    }
    if (st < 6) {
      const int ko = (st + 2) << 5;   // buffer parity (st+2)&1 == cur
      xa[cur][0] = *(const float4*)(px0 + ko);
      xa[cur][1] = *(const float4*)(px0 + ko + 4);
      xb[cur][0] = *(const float4*)(px1 + ko);
      xb[cur][1] = *(const float4*)(px1 + ko + 4);
    }
  }

  // reduce lin/q over the 4 k-groups sharing a row (lanes l ^ {16,32})
  lin0 += __shfl_xor(lin0, 16, 64); lin0 += __shfl_xor(lin0, 32, 64);
  lin1 += __shfl_xor(lin1, 16, 64); lin1 += __shfl_xor(lin1, 32, 64);
  q0   += __shfl_xor(q0,   16, 64); q0   += __shfl_xor(q0,   32, 64);
  q1   += __shfl_xor(q1,   16, 64); q1   += __shfl_xor(q1,   32, 64);
  if (lk == 0) {
    atomicAdd(&lds_lin[l15],      lin0);
    atomicAdd(&lds_lin[16 + l15], lin1);
    atomicAdd(&lds_q[l15],        q0);
    atomicAdd(&lds_q[16 + l15],   q1);
  }

  // accumulate partial xv into LDS (C/D layout: col=l&15, row=(l>>4)*4+j)
  #pragma unroll
  for (int t = 0; t < 2; ++t)
    #pragma unroll
    for (int c = 0; c < 4; ++c)
      #pragma unroll
      for (int j = 0; j < 4; ++j)
        atomicAdd(&lds_xv[t * 16 + lk * 4 + j][c * 16 + l15], acc[t][c][j]);

  __syncthreads();

  // final: thread -> (row = tid>>4, colgroup = tid&15); reduce cols, sigmoid
  {
    const int row = tid >> 4;
    const int cg  = tid & 15;
    float4 s = *(const float4*)&lds_xv[row][cg << 2];
    float ss = s.x * s.x + s.y * s.y + s.z * s.z + s.w * s.w;
    ss += __shfl_xor(ss, 1, 64);
    ss += __shfl_xor(ss, 2, 64);
    ss += __shfl_xor(ss, 4, 64);
    ss += __shfl_xor(ss, 8, 64);
    if (cg == 0) {
      float z = lds_lin[row] + bptr[0] + 0.5f * (ss - lds_q[row]);
      out[R + row] = 1.f / (1.f + expf(-z));
    }
  }
}

extern "C" void kernel_launch(void* const* d_in, const int* in_sizes, int n_in,
                              void* d_out, int out_size, void* d_ws, size_t ws_size,
                              hipStream_t stream) {
  const float* x = (const float*)d_in[0];
  const float* w = (const float*)d_in[1];
  const float* b = (const float*)d_in[2];
  const float* v = (const float*)d_in[3];
  float* out = (float*)d_out;

  // ws layout: [0,256K) v_hi bf16 frags | [256K,512K) v_lo | [512K,520K) S2 f32
  ushort_t* hi = (ushort_t*)d_ws;
  ushort_t* lo = hi + FD * 64;
  float*    s2 = (float*)((char*)d_ws + (size_t)FD * 64 * 2 * sizeof(ushort_t));

  fm_prep<<<520, 256, 0, stream>>>(v, hi, lo, s2);
  fm_main<<<512, 512, 0, stream>>>(x, w, b, (const short8*)hi, (const short8*)lo, s2, out);
}